// Round 2
// baseline (151.370 us; speedup 1.0000x reference)
//
#include <hip/hip_runtime.h>

// YOLO loss: pred (B,30,7,7) f32, label (B,30,7,7) f32 -> scalar f32 (sum/B).
// Memory-bound streaming kernel: 96.3 MB read once -> roofline ~15.3 us @6.3TB/s.
// Strategy: each block stages WB whole batches into LDS with coalesced float4
// loads (16 B/lane), then one thread per (b,i,j) cell computes from LDS.
// WB=2 -> 23.5 KB LDS -> 6 blocks/CU (24 waves/CU) for latency hiding.

constexpr int WB = 2;            // batches per block
constexpr int NT = 256;          // threads per block
constexpr int CH = 30;
constexpr int SC = 49;           // 7*7 cells
constexpr int BF = CH * SC;      // 1470 floats per batch

__device__ __forceinline__ float sq(float x) { return x * x; }

__global__ __launch_bounds__(NT) void yolo_loss_kernel(
    const float* __restrict__ pred, const float* __restrict__ label,
    float* __restrict__ out, int nbatch, float inv_B)
{
    __shared__ float sp[WB * BF];
    __shared__ float sl[WB * BF];
    __shared__ float swave[NT / 64];

    const int t = threadIdx.x;
    const int b0 = blockIdx.x * WB;
    const int nb = min(WB, nbatch - b0);
    const int nfloat = nb * BF;

    const float* __restrict__ gp = pred  + (size_t)b0 * BF;
    const float* __restrict__ gl = label + (size_t)b0 * BF;

    if (nfloat == WB * BF) {
        // fast path: WB*BF = 2940 floats = 735 float4 (block base is 16B-aligned:
        // blockIdx * 2*1470*4 B = 11760 B, multiple of 16)
        const float4* __restrict__ p4 = (const float4*)gp;
        const float4* __restrict__ l4 = (const float4*)gl;
        float4* sp4 = (float4*)sp;
        float4* sl4 = (float4*)sl;
        constexpr int NV = WB * BF / 4;  // 735
        for (int idx = t; idx < NV; idx += NT) {
            sp4[idx] = p4[idx];
            sl4[idx] = l4[idx];
        }
    } else {
        // tail path (never taken for B=8192, kept for safety)
        for (int idx = t; idx < nfloat; idx += NT) {
            sp[idx] = gp[idx];
            sl[idx] = gl[idx];
        }
    }
    __syncthreads();

    const float Gc = 1.0f / 7.0f;
    float cell = 0.0f;
    if (t < nb * SC) {
        int bl = t / SC;
        int s  = t - bl * SC;
        int i = s / 7;          // axis 2, paired with x
        int j = s - i * 7;      // axis 3, paired with y
        const float* __restrict__ p = sp + bl * BF + s;
        const float* __restrict__ l = sl + bl * BF + s;

        // LDS reads: lanes have consecutive s -> consecutive banks, <=2-way (free)
        float pv[CH], lv[CH];
#pragma unroll
        for (int c = 0; c < CH; ++c) {
            pv[c] = p[c * SC];
            lv[c] = l[c * SC];
        }

        float fi = (float)i, fj = (float)j;

        // box 1 (pred ch 0..3)
        float cx1 = (pv[0] + fi) * Gc, cy1 = (pv[1] + fj) * Gc;
        float a_x1 = cx1 - pv[2] * 0.5f, a_y1 = cy1 - pv[3] * 0.5f;
        float a_x2 = cx1 + pv[2] * 0.5f, a_y2 = cy1 + pv[3] * 0.5f;
        // box 2 (pred ch 5..8)
        float cx2 = (pv[5] + fi) * Gc, cy2 = (pv[6] + fj) * Gc;
        float b_x1 = cx2 - pv[7] * 0.5f, b_y1 = cy2 - pv[8] * 0.5f;
        float b_x2 = cx2 + pv[7] * 0.5f, b_y2 = cy2 + pv[8] * 0.5f;
        // degenerate label point-box
        float lx = (lv[0] + fi) * Gc - lv[2] * 0.5f;
        float ly = (lv[1] + fj) * Gc - lv[3] * 0.5f;

        // iou(box, point-box) — faithful to reference (area_b = 0)
        auto iou_pt = [&](float x1, float y1, float x2, float y2) {
            float ix = fminf(x2, lx) - fmaxf(x1, lx);
            float iy = fminf(y2, ly) - fmaxf(y1, ly);
            float inter = fmaxf(ix, 0.0f) * fmaxf(iy, 0.0f);
            float area_a = (x2 - x1) * (y2 - y1);
            float uni = area_a + 0.0f - inter;
            float denom = (uni == 0.0f) ? 1.0f : uni;
            return inter / denom;
        };

        float iou1 = iou_pt(a_x1, a_y1, a_x2, a_y2);
        float iou2 = iou_pt(b_x1, b_y1, b_x2, b_y2);
        bool sel1 = iou1 > iou2;

        float t1 = sq(pv[0] - lv[0]) + sq(pv[1] - lv[1])
                 + sq(sqrtf(pv[2]) - sqrtf(lv[2])) + sq(sqrtf(pv[3]) - sqrtf(lv[3]));
        float t2 = sq(pv[5] - lv[5]) + sq(pv[6] - lv[6])
                 + sq(sqrtf(pv[7]) - sqrtf(lv[7])) + sq(sqrtf(pv[8]) - sqrtf(lv[8]));

        float obj_term     = sel1 ? t1 : t2;
        float conf_term    = sel1 ? sq(pv[4] - 1.0f) : sq(pv[9] - 1.0f);
        float noobj_obj    = sel1 ? sq(pv[9]) : sq(pv[4]);
        float noobj_empty  = sq(pv[4]) + sq(pv[9]);

        float cls = 0.0f;
#pragma unroll
        for (int c = 10; c < CH; ++c) cls += sq(pv[c] - lv[c]);

        bool obj = (lv[4] == 1.0f);
        // obj_weight = 0.5, noobj_weight = 0.5
        cell = obj ? (0.5f * obj_term + conf_term + cls + 0.5f * noobj_obj)
                   : (0.5f * noobj_empty);
    }

    // wave (64-lane) shuffle reduce
#pragma unroll
    for (int off = 32; off > 0; off >>= 1)
        cell += __shfl_down(cell, off, 64);

    int lane = t & 63;
    int wid  = t >> 6;
    if (lane == 0) swave[wid] = cell;
    __syncthreads();
    if (t == 0) {
        float bs = swave[0] + swave[1] + swave[2] + swave[3];
        atomicAdd(out, bs * inv_B);
    }
}

extern "C" void kernel_launch(void* const* d_in, const int* in_sizes, int n_in,
                              void* d_out, int out_size, void* d_ws, size_t ws_size,
                              hipStream_t stream) {
    const float* pred  = (const float*)d_in[0];
    const float* label = (const float*)d_in[1];
    float* out = (float*)d_out;

    int B = in_sizes[0] / BF;

    hipMemsetAsync(d_out, 0, sizeof(float), stream);

    int grid = (B + WB - 1) / WB;
    yolo_loss_kernel<<<grid, NT, 0, stream>>>(pred, label, out, B,
                                              1.0f / (float)B);
}

// Round 3
// 117.367 us; speedup vs baseline: 1.2897x; 1.2897x over previous
//
#include <hip/hip_runtime.h>

// YOLO loss: pred (B,30,7,7) f32, label (B,30,7,7) f32 -> scalar f32 (sum/B).
// Memory-bound: 96.3 MB read once -> ~15.3 us floor @6.3 TB/s (less w/ L3 hits).
//
// R2 post-mortem: 4096 same-address atomicAdds serialized at one TCC channel
// (~15 ns each ~= the whole 62 us). Fix: grid-stride with 256 blocks -> 256
// atomics total. Loads stay stride-49 dwords (cell-consecutive lanes -> ~256 B
// coalesced segments per wave instruction); each thread handles ~3 cells for
// deep memory-level parallelism.

constexpr int NT = 512;   // threads per block (8 waves)
constexpr int NB = 256;   // blocks (1 per CU); 256 atomics total

__device__ __forceinline__ float sq(float x) { return x * x; }

__global__ __launch_bounds__(NT) void yolo_loss_kernel(
    const float* __restrict__ pred, const float* __restrict__ label,
    float* __restrict__ out, int ncells, float inv_B)
{
    const float Gc = 1.0f / 7.0f;
    float acc = 0.0f;

    for (int g = blockIdx.x * NT + threadIdx.x; g < ncells; g += NB * NT) {
        int b = g / 49;
        int s = g - b * 49;
        int i = s / 7;          // axis 2, paired with x
        int j = s - i * 7;      // axis 3, paired with y
        const float* __restrict__ P = pred  + (size_t)b * 1470 + s;
        const float* __restrict__ L = label + (size_t)b * 1470 + s;

        float p[30], l[30];
#pragma unroll
        for (int c = 0; c < 30; ++c) {
            p[c] = P[c * 49];
            l[c] = L[c * 49];
        }

        float fi = (float)i, fj = (float)j;

        // box 1 (pred ch 0..3)
        float cx1 = (p[0] + fi) * Gc, cy1 = (p[1] + fj) * Gc;
        float a_x1 = cx1 - p[2] * 0.5f, a_y1 = cy1 - p[3] * 0.5f;
        float a_x2 = cx1 + p[2] * 0.5f, a_y2 = cy1 + p[3] * 0.5f;
        // box 2 (pred ch 5..8)
        float cx2 = (p[5] + fi) * Gc, cy2 = (p[6] + fj) * Gc;
        float b_x1 = cx2 - p[7] * 0.5f, b_y1 = cy2 - p[8] * 0.5f;
        float b_x2 = cx2 + p[7] * 0.5f, b_y2 = cy2 + p[8] * 0.5f;
        // degenerate label point-box
        float lx = (l[0] + fi) * Gc - l[2] * 0.5f;
        float ly = (l[1] + fj) * Gc - l[3] * 0.5f;

        // iou(box, point-box) — faithful to reference (area_b = 0)
        auto iou_pt = [&](float x1, float y1, float x2, float y2) {
            float ix = fminf(x2, lx) - fmaxf(x1, lx);
            float iy = fminf(y2, ly) - fmaxf(y1, ly);
            float inter = fmaxf(ix, 0.0f) * fmaxf(iy, 0.0f);
            float area_a = (x2 - x1) * (y2 - y1);
            float uni = area_a + 0.0f - inter;
            float denom = (uni == 0.0f) ? 1.0f : uni;
            return inter / denom;
        };

        float iou1 = iou_pt(a_x1, a_y1, a_x2, a_y2);
        float iou2 = iou_pt(b_x1, b_y1, b_x2, b_y2);
        bool sel1 = iou1 > iou2;

        float t1 = sq(p[0] - l[0]) + sq(p[1] - l[1])
                 + sq(sqrtf(p[2]) - sqrtf(l[2])) + sq(sqrtf(p[3]) - sqrtf(l[3]));
        float t2 = sq(p[5] - l[5]) + sq(p[6] - l[6])
                 + sq(sqrtf(p[7]) - sqrtf(l[7])) + sq(sqrtf(p[8]) - sqrtf(l[8]));

        float obj_term     = sel1 ? t1 : t2;
        float conf_term    = sel1 ? sq(p[4] - 1.0f) : sq(p[9] - 1.0f);
        float noobj_obj    = sel1 ? sq(p[9]) : sq(p[4]);
        float noobj_empty  = sq(p[4]) + sq(p[9]);

        float cls = 0.0f;
#pragma unroll
        for (int c = 10; c < 30; ++c) cls += sq(p[c] - l[c]);

        bool obj = (l[4] == 1.0f);
        // obj_weight = 0.5, noobj_weight = 0.5
        acc += obj ? (0.5f * obj_term + conf_term + cls + 0.5f * noobj_obj)
                   : (0.5f * noobj_empty);
    }

    // wave (64-lane) shuffle reduce
#pragma unroll
    for (int off = 32; off > 0; off >>= 1)
        acc += __shfl_down(acc, off, 64);

    __shared__ float swave[NT / 64];
    int lane = threadIdx.x & 63;
    int wid  = threadIdx.x >> 6;
    if (lane == 0) swave[wid] = acc;
    __syncthreads();
    if (threadIdx.x == 0) {
        float bs = 0.0f;
#pragma unroll
        for (int w = 0; w < NT / 64; ++w) bs += swave[w];
        atomicAdd(out, bs * inv_B);   // 256 atomics total
    }
}

extern "C" void kernel_launch(void* const* d_in, const int* in_sizes, int n_in,
                              void* d_out, int out_size, void* d_ws, size_t ws_size,
                              hipStream_t stream) {
    const float* pred  = (const float*)d_in[0];
    const float* label = (const float*)d_in[1];
    float* out = (float*)d_out;

    int B = in_sizes[0] / 1470;
    int ncells = B * 49;

    hipMemsetAsync(d_out, 0, sizeof(float), stream);

    yolo_loss_kernel<<<NB, NT, 0, stream>>>(pred, label, out, ncells,
                                            1.0f / (float)B);
}

// Round 4
// 113.635 us; speedup vs baseline: 1.3321x; 1.0328x over previous
//
#include <hip/hip_runtime.h>

// YOLO loss: pred (B,30,7,7) f32, label (B,30,7,7) f32 -> scalar f32 (sum/B).
// Memory-bound: 96.3 MB read once -> ~15.3 us floor @6.3 TB/s (less w/ L3 hits).
//
// R3 post-mortem: 256 blocks x 512 thr = 1 block/CU = 2 waves/SIMD — marginal
// MLP for ~900-cyc HBM latency. R4: 512 blocks -> 2 blocks/CU, 4 waves/SIMD,
// 512 staggered per-block atomics (tail hidden by uneven block finish times).
// Loads stay stride-49 dwords: 64 consecutive cells/wave -> contiguous 196-256 B
// segments, already fully coalesced; issue rate is not the limiter (VALUBusy 8%).

constexpr int NT = 512;   // threads per block (8 waves)
constexpr int NB = 512;   // blocks (2 per CU, 16 waves/CU)

__device__ __forceinline__ float sq(float x) { return x * x; }

__global__ __launch_bounds__(NT) void yolo_loss_kernel(
    const float* __restrict__ pred, const float* __restrict__ label,
    float* __restrict__ out, int ncells, float inv_B)
{
    const float Gc = 1.0f / 7.0f;
    float acc = 0.0f;

    for (int g = blockIdx.x * NT + threadIdx.x; g < ncells; g += NB * NT) {
        int b = g / 49;
        int s = g - b * 49;
        int i = s / 7;          // axis 2, paired with x
        int j = s - i * 7;      // axis 3, paired with y
        const float* __restrict__ P = pred  + (size_t)b * 1470 + s;
        const float* __restrict__ L = label + (size_t)b * 1470 + s;

        float p[30], l[30];
#pragma unroll
        for (int c = 0; c < 30; ++c) {
            p[c] = P[c * 49];
            l[c] = L[c * 49];
        }

        float fi = (float)i, fj = (float)j;

        // box 1 (pred ch 0..3)
        float cx1 = (p[0] + fi) * Gc, cy1 = (p[1] + fj) * Gc;
        float a_x1 = cx1 - p[2] * 0.5f, a_y1 = cy1 - p[3] * 0.5f;
        float a_x2 = cx1 + p[2] * 0.5f, a_y2 = cy1 + p[3] * 0.5f;
        // box 2 (pred ch 5..8)
        float cx2 = (p[5] + fi) * Gc, cy2 = (p[6] + fj) * Gc;
        float b_x1 = cx2 - p[7] * 0.5f, b_y1 = cy2 - p[8] * 0.5f;
        float b_x2 = cx2 + p[7] * 0.5f, b_y2 = cy2 + p[8] * 0.5f;
        // degenerate label point-box
        float lx = (l[0] + fi) * Gc - l[2] * 0.5f;
        float ly = (l[1] + fj) * Gc - l[3] * 0.5f;

        // iou(box, point-box) — faithful to reference (area_b = 0)
        auto iou_pt = [&](float x1, float y1, float x2, float y2) {
            float ix = fminf(x2, lx) - fmaxf(x1, lx);
            float iy = fminf(y2, ly) - fmaxf(y1, ly);
            float inter = fmaxf(ix, 0.0f) * fmaxf(iy, 0.0f);
            float area_a = (x2 - x1) * (y2 - y1);
            float uni = area_a + 0.0f - inter;
            float denom = (uni == 0.0f) ? 1.0f : uni;
            return inter / denom;
        };

        float iou1 = iou_pt(a_x1, a_y1, a_x2, a_y2);
        float iou2 = iou_pt(b_x1, b_y1, b_x2, b_y2);
        bool sel1 = iou1 > iou2;

        float t1 = sq(p[0] - l[0]) + sq(p[1] - l[1])
                 + sq(sqrtf(p[2]) - sqrtf(l[2])) + sq(sqrtf(p[3]) - sqrtf(l[3]));
        float t2 = sq(p[5] - l[5]) + sq(p[6] - l[6])
                 + sq(sqrtf(p[7]) - sqrtf(l[7])) + sq(sqrtf(p[8]) - sqrtf(l[8]));

        float obj_term     = sel1 ? t1 : t2;
        float conf_term    = sel1 ? sq(p[4] - 1.0f) : sq(p[9] - 1.0f);
        float noobj_obj    = sel1 ? sq(p[9]) : sq(p[4]);
        float noobj_empty  = sq(p[4]) + sq(p[9]);

        float cls = 0.0f;
#pragma unroll
        for (int c = 10; c < 30; ++c) cls += sq(p[c] - l[c]);

        bool obj = (l[4] == 1.0f);
        // obj_weight = 0.5, noobj_weight = 0.5
        acc += obj ? (0.5f * obj_term + conf_term + cls + 0.5f * noobj_obj)
                   : (0.5f * noobj_empty);
    }

    // wave (64-lane) shuffle reduce
#pragma unroll
    for (int off = 32; off > 0; off >>= 1)
        acc += __shfl_down(acc, off, 64);

    __shared__ float swave[NT / 64];
    int lane = threadIdx.x & 63;
    int wid  = threadIdx.x >> 6;
    if (lane == 0) swave[wid] = acc;
    __syncthreads();
    if (threadIdx.x == 0) {
        float bs = 0.0f;
#pragma unroll
        for (int w = 0; w < NT / 64; ++w) bs += swave[w];
        atomicAdd(out, bs * inv_B);   // 512 atomics total, staggered
    }
}

extern "C" void kernel_launch(void* const* d_in, const int* in_sizes, int n_in,
                              void* d_out, int out_size, void* d_ws, size_t ws_size,
                              hipStream_t stream) {
    const float* pred  = (const float*)d_in[0];
    const float* label = (const float*)d_in[1];
    float* out = (float*)d_out;

    int B = in_sizes[0] / 1470;
    int ncells = B * 49;

    hipMemsetAsync(d_out, 0, sizeof(float), stream);

    yolo_loss_kernel<<<NB, NT, 0, stream>>>(pred, label, out, ncells,
                                            1.0f / (float)B);
}